// Round 6
// baseline (190.876 us; speedup 1.0000x reference)
//
#include <hip/hip_runtime.h>
#include <float.h>
#include <math.h>

// NPairLoss MI355X r6: r5 + spill fix + launch-count reduction.
// 4 nodes: prep (bf16 convert + sq) -> classsel (per-class LDS bucket: gumbel argmax +
// exact numerator) -> fused (A-register-resident MFMA gram + masked online-lse,
// __launch_bounds__(256,2) so nothing spills) -> finale (combine 16 partials + loss).
// ws ~5.1 MB.

#define B_N 8192
#define D_K 256
#define NCLS 100
#define MAXC 512
#define NSPLIT 16
#define NPART NSPLIT
#define JR (B_N / NSPLIT)      // 512
#define BI 128
#define BJ 128
#define NJT (JR / BJ)          // 4
#define BK 64
#define NKC (D_K / BK)         // 4
#define NEG_INF -1e30f

typedef __attribute__((ext_vector_type(8))) short bf16x8;
typedef __attribute__((ext_vector_type(4))) float f32x4;
typedef unsigned short ushort_t;

// ---------------- threefry2x32 / jax gumbel (bit-exact, known-good) ----------------
__device__ __forceinline__ unsigned rotl32(unsigned x, int d){ return (x << d) | (x >> (32 - d)); }

__device__ __forceinline__ float gumbel_at(unsigned idx){
  const unsigned HALF = (unsigned)B_N * (unsigned)B_N / 2u;
  unsigned c0, c1; bool second;
  if (idx < HALF){ c0 = idx; c1 = idx + HALF; second = false; }
  else            { c0 = idx - HALF; c1 = idx; second = true; }
  const unsigned ks0 = 0u, ks1 = 42u, ks2 = 0u ^ 42u ^ 0x1BD11BDAu;
  unsigned x0 = c0 + ks0, x1 = c1 + ks1;
#define TF_RND(r) { x0 += x1; x1 = rotl32(x1, (r)); x1 ^= x0; }
  TF_RND(13) TF_RND(15) TF_RND(26) TF_RND(6)   x0 += ks1; x1 += ks2 + 1u;
  TF_RND(17) TF_RND(29) TF_RND(16) TF_RND(24)  x0 += ks2; x1 += ks0 + 2u;
  TF_RND(13) TF_RND(15) TF_RND(26) TF_RND(6)   x0 += ks0; x1 += ks1 + 3u;
  TF_RND(17) TF_RND(29) TF_RND(16) TF_RND(24)  x0 += ks1; x1 += ks2 + 4u;
  TF_RND(13) TF_RND(15) TF_RND(26) TF_RND(6)   x0 += ks2; x1 += ks0 + 5u;
#undef TF_RND
  unsigned bits = second ? x1 : x0;
  float u = __uint_as_float((bits >> 9) | 0x3f800000u) - 1.0f;
  const float TINY = 1.17549435e-38f;
  u = u * (1.0f - TINY) + TINY;
  u = fmaxf(TINY, u);
  return -logf(-logf(u));
}

__device__ __forceinline__ ushort_t f2bf(float x){
  unsigned u = __float_as_uint(x);
  return (ushort_t)((u + 0x7FFFu + ((u >> 16) & 1u)) >> 16); // RNE
}

__device__ __forceinline__ void async16(const ushort_t* g, ushort_t* lds_wave_base){
  __builtin_amdgcn_global_load_lds((const __attribute__((address_space(1))) void*)g,
                                   (__attribute__((address_space(3))) void*)lds_wave_base,
                                   16, 0, 0);
}

// ---------------- node 1. prep: E fp32 -> bf16, sq[i] (exact fp32) ----------------
__global__ void prep_kernel(const float* __restrict__ E, ushort_t* __restrict__ Ebf,
                            float* __restrict__ sq){
  int w = threadIdx.x >> 6, lane = threadIdx.x & 63;
  int row = blockIdx.x * 4 + w;
  const float4 v = *reinterpret_cast<const float4*>(E + (size_t)row * D_K + lane * 4);
  float s = v.x*v.x + v.y*v.y + v.z*v.z + v.w*v.w;
#pragma unroll
  for (int off = 32; off > 0; off >>= 1) s += __shfl_down(s, off);
  if (lane == 0) sq[row] = s;
  ushort4 o; o.x = f2bf(v.x); o.y = f2bf(v.y); o.z = f2bf(v.z); o.w = f2bf(v.w);
  *reinterpret_cast<ushort4*>(Ebf + (size_t)row * D_K + lane * 4) = o;
}

// ---------------- node 2. classsel: one block per class ----------------
// Build the class member list in LDS (order-independent result), then per member row:
// gumbel-argmax positive (bit-exact jax stream, smallest-j tie-break == jnp.argmax)
// + fp32-exact numerator dot.
__global__ __launch_bounds__(256)
void classsel_kernel(const float* __restrict__ E, const int* __restrict__ labels,
                     const float* __restrict__ sq,
                     int* __restrict__ jsel, float* __restrict__ numer){
  __shared__ int s_list[MAXC];
  __shared__ int s_n;
  const int c = blockIdx.x;
  const int tid = threadIdx.x, w = tid >> 6, lane = tid & 63;
  if (tid == 0) s_n = 0;
  __syncthreads();
  for (int t = tid; t < B_N; t += 256){
    if (labels[t] == c){
      int p = atomicAdd(&s_n, 1);
      if (p < MAXC) s_list[p] = t;
    }
  }
  __syncthreads();
  const int n = min(s_n, MAXC);
  // each wave handles member rows strided by 4
  for (int idx = w; idx < n; idx += 4){
    const int row = s_list[idx];
    float gb = -FLT_MAX; int jb = 0x7FFFFFFF;
    for (int t = lane; t < n; t += 64){
      int j = s_list[t];
      if (j != row){
        float g = gumbel_at(((unsigned)row << 13) + (unsigned)j);
        if (g > gb || (g == gb && j < jb)){ gb = g; jb = j; }
      }
    }
#pragma unroll
    for (int mask = 1; mask < 64; mask <<= 1){
      float g2 = __shfl_xor(gb, mask);
      int   j2 = __shfl_xor(jb, mask);
      if (g2 > gb || (g2 == gb && j2 < jb)){ gb = g2; jb = j2; }
    }
    if (jb == 0x7FFFFFFF){
      if (lane == 0){ jsel[row] = -1; numer[row] = 0.f; }
      continue;
    }
    const float4 a = *reinterpret_cast<const float4*>(E + (size_t)row * D_K + lane * 4);
    const float4 b = *reinterpret_cast<const float4*>(E + (size_t)jb  * D_K + lane * 4);
    float d = a.x*b.x + a.y*b.y + a.z*b.z + a.w*b.w;
#pragma unroll
    for (int off = 32; off > 0; off >>= 1) d += __shfl_down(d, off);
    if (lane == 0){
      jsel[row] = jb;
      numer[row] = -10.f * fmaxf(sq[row] + sq[jb] - 2.f * d, 0.f);
    }
  }
}

// ---------------- node 3. fused: A-resident MFMA gram + masked online-lse ----------------
__global__ __launch_bounds__(256, 2)   // 2 blocks/CU: 256 regs/thread -> NO spill
void fused_kernel(const ushort_t* __restrict__ Ebf, const int* __restrict__ labels,
                  const float* __restrict__ sq,
                  float* __restrict__ wsM, float* __restrict__ wsS)
{
  __shared__ __align__(16) ushort_t Bs[BJ * BK];  // 16 KB, XOR-swizzled 16B groups
  __shared__ float s_sqj[JR];   // 2 KB
  __shared__ int   s_lj[JR];    // 2 KB
  __shared__ float s_sqi[BI];
  __shared__ int   s_li[BI];

  const int bi    = blockIdx.x >> 4;         // 0..63
  const int split = blockIdx.x & 15;         // 0..15
  const int i0    = bi * BI;
  const int jbase = split * JR;
  const int tid   = threadIdx.x;
  const int lane  = tid & 63;
  const int w     = tid >> 6;                // wave 0..3, owns rows [w*32, w*32+32)
  const int quad  = lane >> 4;
  const int l15   = lane & 15;

  for (int t = tid; t < JR; t += 256){ s_sqj[t] = sq[jbase + t]; s_lj[t] = labels[jbase + t]; }
  if (tid < BI){ s_sqi[tid] = sq[i0 + tid]; s_li[tid] = labels[i0 + tid]; }

  // A fragments: wave's 32 rows x K=256, register-resident (64 VGPRs).
  bf16x8 af[2][8];
#pragma unroll
  for (int mt = 0; mt < 2; mt++){
    const ushort_t* rp = Ebf + (size_t)(i0 + w * 32 + mt * 16 + l15) * D_K + quad * 8;
#pragma unroll
    for (int c = 0; c < 8; c++)
      af[mt][c] = *reinterpret_cast<const bf16x8*>(rp + c * 32);
  }

  float sm[8], ssum[8];
#pragma unroll
  for (int r = 0; r < 8; r++){ sm[r] = NEG_INF; ssum[r] = 0.f; }

  __syncthreads();  // s_sqj/s_lj ready

  for (int jt = 0; jt < NJT; jt++){
    const int j0 = jbase + jt * BJ;
    f32x4 acc[2][8];
#pragma unroll
    for (int mt = 0; mt < 2; mt++)
#pragma unroll
      for (int nt = 0; nt < 8; nt++) acc[mt][nt] = (f32x4)0.f;

    for (int kc = 0; kc < NKC; kc++){
      const int koff = kc * BK;
      __syncthreads();                       // protect Bs from previous consumers
#pragma unroll
      for (int rd = 0; rd < 4; rd++){
        int slot = rd * 256 + tid;           // 1024 slots of 16B: row = slot>>3, group = slot&7
        int r = slot >> 3, gs = slot & 7;
        int gsrc = (gs ^ (r & 7)) << 3;      // swizzle on the gather side
        ushort_t* ldsB = Bs + (size_t)(rd * 256 + w * 64) * 8;
        async16(Ebf + (size_t)(j0 + r) * D_K + koff + gsrc, ldsB);
      }
      __syncthreads();                       // staged (vmcnt drained before barrier)
#pragma unroll
      for (int s = 0; s < 2; s++){
        const int g = s * 4 + quad;          // k-group within 64-chunk
        const int c = kc * 2 + s;            // global 32-k chunk index for A frags
        bf16x8 bfr[8];
#pragma unroll
        for (int nt = 0; nt < 8; nt++){
          int r = nt * 16 + l15;
          bfr[nt] = *reinterpret_cast<const bf16x8*>(&Bs[r * BK + ((g ^ (r & 7)) << 3)]);
        }
#pragma unroll
        for (int nt = 0; nt < 8; nt++){
          acc[0][nt] = __builtin_amdgcn_mfma_f32_16x16x32_bf16(af[0][c], bfr[nt], acc[0][nt], 0, 0, 0);
          acc[1][nt] = __builtin_amdgcn_mfma_f32_16x16x32_bf16(af[1][c], bfr[nt], acc[1][nt], 0, 0, 0);
        }
      }
    }

    // ---- epilogue for this 128-col tile (wave-exclusive rows) ----
    float sqj[8]; int lj[8];
#pragma unroll
    for (int nt = 0; nt < 8; nt++){
      int ccol = jt * BJ + nt * 16 + l15;
      sqj[nt] = s_sqj[ccol]; lj[nt] = s_lj[ccol];
    }
#pragma unroll
    for (int mt = 0; mt < 2; mt++){
#pragma unroll
      for (int rr = 0; rr < 4; rr++){
        int rl = w * 32 + mt * 16 + quad * 4 + rr;   // C/D: row = quad*4+reg, col = l15
        float sqv = s_sqi[rl]; int lrow = s_li[rl];
        int sidx = mt * 4 + rr;
        float sv[8];
#pragma unroll
        for (int nt = 0; nt < 8; nt++){
          float a = acc[mt][nt][rr];
          float simv = -10.f * fmaxf(fmaf(-2.f, a, sqv + sqj[nt]), 0.f);
          sv[nt] = (lj[nt] != lrow) ? simv : NEG_INF;  // masks positives + same-label + diag
        }
        float m8 = fmaxf(fmaxf(fmaxf(sv[0],sv[1]),fmaxf(sv[2],sv[3])),
                         fmaxf(fmaxf(sv[4],sv[5]),fmaxf(sv[6],sv[7])));
        float s8 = __expf(sv[0]-m8)+__expf(sv[1]-m8)+__expf(sv[2]-m8)+__expf(sv[3]-m8)
                 + __expf(sv[4]-m8)+__expf(sv[5]-m8)+__expf(sv[6]-m8)+__expf(sv[7]-m8);
        float M = fmaxf(sm[sidx], m8);
        ssum[sidx] = ssum[sidx]*__expf(sm[sidx]-M) + s8*__expf(m8-M);
        sm[sidx] = M;
      }
    }
  }

  // merge the 16 l15-lanes sharing each row; rows are wave-exclusive -> one slot per split
#pragma unroll
  for (int sidx = 0; sidx < 8; sidx++){
    float mv = sm[sidx], sv2 = ssum[sidx];
#pragma unroll
    for (int mask = 1; mask < 16; mask <<= 1){
      float m2 = __shfl_xor(mv, mask);
      float s2 = __shfl_xor(sv2, mask);
      float M = fmaxf(mv, m2);
      sv2 = sv2 * __expf(mv - M) + s2 * __expf(m2 - M);
      mv = M;
    }
    if (l15 == 0){
      int mt = sidx >> 2, rr = sidx & 3;
      int rl = w * 32 + mt * 16 + quad * 4 + rr;
      int o = split * B_N + i0 + rl;
      wsM[o] = mv; wsS[o] = sv2;
    }
  }
}

// ---------------- node 4. finale: combine 16 partials per row + mean over valid ----------------
__global__ __launch_bounds__(1024)
void finale_kernel(const float* __restrict__ wsM, const float* __restrict__ wsS,
                   const float* __restrict__ numer, const int* __restrict__ jsel,
                   float* __restrict__ out)
{
  int tid = threadIdx.x;
  float s = 0.f; unsigned n = 0u;
  for (int row = tid; row < B_N; row += 1024){
    float M = -3.0e38f, S = 0.f;
#pragma unroll
    for (int p = 0; p < NPART; p++){
      float m2 = wsM[p * B_N + row], s2 = wsS[p * B_N + row];
      float Mn = fmaxf(M, m2);
      S = S * __expf(M - Mn) + s2 * __expf(m2 - Mn);
      M = Mn;
    }
    bool v = (jsel[row] >= 0) && (M > -5e29f);
    if (v){ s += M + logf(S) - numer[row]; n += 1u; }
  }
#pragma unroll
  for (int off = 32; off > 0; off >>= 1){ s += __shfl_down(s, off); n += __shfl_down(n, off); }
  __shared__ float ssm[16]; __shared__ unsigned snm[16];
  if ((tid & 63) == 0){ ssm[tid >> 6] = s; snm[tid >> 6] = n; }
  __syncthreads();
  if (tid == 0){
    float S = 0.f; unsigned N = 0u;
#pragma unroll
    for (int i = 0; i < 16; i++){ S += ssm[i]; N += snm[i]; }
    out[0] = (N > 0u) ? (S / (float)N) : 0.f;
  }
}

extern "C" void kernel_launch(void* const* d_in, const int* in_sizes, int n_in,
                              void* d_out, int out_size, void* d_ws, size_t ws_size,
                              hipStream_t stream)
{
  const float* E      = (const float*)d_in[0];
  const int*   labels = (const int*)d_in[1];
  float*       out    = (float*)d_out;

  ushort_t* Ebf = (ushort_t*)d_ws;                     // 4 MB
  float* wsM    = (float*)(Ebf + (size_t)B_N * D_K);   // 512 KB (16 partials)
  float* wsS    = wsM + NPART * B_N;                   // 512 KB
  float* sqb    = wsS + NPART * B_N;                   // 32 KB
  float* numer  = sqb + B_N;                           // 32 KB
  int* jsel     = (int*)(numer + B_N);                 // 32 KB

  prep_kernel<<<B_N / 4, 256, 0, stream>>>(E, Ebf, sqb);
  classsel_kernel<<<NCLS, 256, 0, stream>>>(E, labels, sqb, jsel, numer);
  fused_kernel<<<(B_N / BI) * NSPLIT, 256, 0, stream>>>(Ebf, labels, sqb, wsM, wsS);
  finale_kernel<<<1, 1024, 0, stream>>>(wsM, wsS, numer, jsel, out);
}

// Round 7
// 164.237 us; speedup vs baseline: 1.1622x; 1.1622x over previous
//
#include <hip/hip_runtime.h>
#include <float.h>
#include <math.h>

// NPairLoss MI355X r7.
// prep (bf16 convert + sq + zero accumulators) -> classsel (per-class bucket, one THREAD
// per row gumbel argmax) -> fused (A-register-resident MFMA gram, full-K B-slab staged
// once per jt => 8 barriers/block, numerator extracted in epilogue) -> finale (32 blocks,
// atomic-finish reduction).  ws ~5.1 MB.

#define B_N 8192
#define D_K 256
#define NCLS 100
#define MAXC 512
#define NSPLIT 16
#define NPART NSPLIT
#define JR (B_N / NSPLIT)      // 512
#define BI 128
#define BJ 128
#define NJT (JR / BJ)          // 4
#define BK 64
#define NKC (D_K / BK)         // 4
#define NEG_INF -1e30f

typedef __attribute__((ext_vector_type(8))) short bf16x8;
typedef __attribute__((ext_vector_type(4))) float f32x4;
typedef unsigned short ushort_t;

// ---------------- threefry2x32 / jax gumbel (bit-exact, known-good) ----------------
__device__ __forceinline__ unsigned rotl32(unsigned x, int d){ return (x << d) | (x >> (32 - d)); }

__device__ __forceinline__ float gumbel_at(unsigned idx){
  const unsigned HALF = (unsigned)B_N * (unsigned)B_N / 2u;
  unsigned c0, c1; bool second;
  if (idx < HALF){ c0 = idx; c1 = idx + HALF; second = false; }
  else            { c0 = idx - HALF; c1 = idx; second = true; }
  const unsigned ks0 = 0u, ks1 = 42u, ks2 = 0u ^ 42u ^ 0x1BD11BDAu;
  unsigned x0 = c0 + ks0, x1 = c1 + ks1;
#define TF_RND(r) { x0 += x1; x1 = rotl32(x1, (r)); x1 ^= x0; }
  TF_RND(13) TF_RND(15) TF_RND(26) TF_RND(6)   x0 += ks1; x1 += ks2 + 1u;
  TF_RND(17) TF_RND(29) TF_RND(16) TF_RND(24)  x0 += ks2; x1 += ks0 + 2u;
  TF_RND(13) TF_RND(15) TF_RND(26) TF_RND(6)   x0 += ks0; x1 += ks1 + 3u;
  TF_RND(17) TF_RND(29) TF_RND(16) TF_RND(24)  x0 += ks1; x1 += ks2 + 4u;
  TF_RND(13) TF_RND(15) TF_RND(26) TF_RND(6)   x0 += ks2; x1 += ks0 + 5u;
#undef TF_RND
  unsigned bits = second ? x1 : x0;
  float u = __uint_as_float((bits >> 9) | 0x3f800000u) - 1.0f;
  const float TINY = 1.17549435e-38f;
  u = u * (1.0f - TINY) + TINY;
  u = fmaxf(TINY, u);
  return -logf(-logf(u));
}

__device__ __forceinline__ ushort_t f2bf(float x){
  unsigned u = __float_as_uint(x);
  return (ushort_t)((u + 0x7FFFu + ((u >> 16) & 1u)) >> 16); // RNE
}

__device__ __forceinline__ void async16(const ushort_t* g, ushort_t* lds_wave_base){
  __builtin_amdgcn_global_load_lds((const __attribute__((address_space(1))) void*)g,
                                   (__attribute__((address_space(3))) void*)lds_wave_base,
                                   16, 0, 0);
}

// ---------------- node 1. prep: E fp32 -> bf16, sq[i]; block 0 zeroes accumulators ----------------
__global__ void prep_kernel(const float* __restrict__ E, ushort_t* __restrict__ Ebf,
                            float* __restrict__ sq, float* __restrict__ acc4){
  if (blockIdx.x == 0 && threadIdx.x < 4)
    acc4[threadIdx.x] = 0.f;  // [0]=sum, [1]=count(as bits), [2]=done(as bits)
  int w = threadIdx.x >> 6, lane = threadIdx.x & 63;
  int row = blockIdx.x * 4 + w;
  const float4 v = *reinterpret_cast<const float4*>(E + (size_t)row * D_K + lane * 4);
  float s = v.x*v.x + v.y*v.y + v.z*v.z + v.w*v.w;
#pragma unroll
  for (int off = 32; off > 0; off >>= 1) s += __shfl_down(s, off);
  if (lane == 0) sq[row] = s;
  ushort4 o; o.x = f2bf(v.x); o.y = f2bf(v.y); o.z = f2bf(v.z); o.w = f2bf(v.w);
  *reinterpret_cast<ushort4*>(Ebf + (size_t)row * D_K + lane * 4) = o;
}

// ---------------- node 2. classsel: one block per class, one THREAD per member row ----------------
__global__ __launch_bounds__(256)
void classsel_kernel(const int* __restrict__ labels, int* __restrict__ jsel){
  __shared__ int s_list[MAXC];
  __shared__ int s_n;
  const int c = blockIdx.x;
  const int tid = threadIdx.x;
  if (tid == 0) s_n = 0;
  __syncthreads();
  for (int t = tid; t < B_N; t += 256){
    if (labels[t] == c){
      int p = atomicAdd(&s_n, 1);
      if (p < MAXC) s_list[p] = t;
    }
  }
  __syncthreads();
  const int n = min(s_n, MAXC);
  // one thread per member row; inner serial scan over LDS list (broadcast reads)
  for (int rowIdx = tid; rowIdx < n; rowIdx += 256){
    const int row = s_list[rowIdx];
    float gb = -FLT_MAX; int jb = -1;
    for (int t = 0; t < n; t++){
      int j = s_list[t];
      if (j != row){
        float g = gumbel_at(((unsigned)row << 13) + (unsigned)j);
        if (g > gb || (g == gb && (unsigned)j < (unsigned)jb)){ gb = g; jb = j; }
      }
    }
    jsel[row] = jb;  // -1 iff class has a single member (no positive)
  }
}

// ---------------- node 3. fused: A-resident MFMA gram + masked online-lse + numerator ----------------
__global__ __launch_bounds__(256, 2)
void fused_kernel(const ushort_t* __restrict__ Ebf, const int* __restrict__ labels,
                  const float* __restrict__ sq, const int* __restrict__ jsel,
                  float* __restrict__ numer,
                  float* __restrict__ wsM, float* __restrict__ wsS)
{
  __shared__ __align__(16) ushort_t Bs[NKC][BJ * BK];  // 4 x 16 KB, XOR-swizzled 16B groups
  __shared__ float s_sqj[JR];   // 2 KB
  __shared__ int   s_lj[JR];    // 2 KB
  __shared__ float s_sqi[BI];
  __shared__ int   s_li[BI];
  __shared__ int   s_ji[BI];

  const int bi    = blockIdx.x >> 4;         // 0..63
  const int split = blockIdx.x & 15;         // 0..15
  const int i0    = bi * BI;
  const int jbase = split * JR;
  const int tid   = threadIdx.x;
  const int lane  = tid & 63;
  const int w     = tid >> 6;                // wave 0..3, owns rows [w*32, w*32+32)
  const int quad  = lane >> 4;
  const int l15   = lane & 15;

  for (int t = tid; t < JR; t += 256){ s_sqj[t] = sq[jbase + t]; s_lj[t] = labels[jbase + t]; }
  if (tid < BI){ s_sqi[tid] = sq[i0 + tid]; s_li[tid] = labels[i0 + tid]; s_ji[tid] = jsel[i0 + tid]; }

  // A fragments: wave's 32 rows x K=256, register-resident (64 regs).
  bf16x8 af[2][8];
#pragma unroll
  for (int mt = 0; mt < 2; mt++){
    const ushort_t* rp = Ebf + (size_t)(i0 + w * 32 + mt * 16 + l15) * D_K + quad * 8;
#pragma unroll
    for (int c = 0; c < 8; c++)
      af[mt][c] = *reinterpret_cast<const bf16x8*>(rp + c * 32);
  }

  float sm[8], ssum[8];
#pragma unroll
  for (int r = 0; r < 8; r++){ sm[r] = NEG_INF; ssum[r] = 0.f; }

  __syncthreads();  // s_* ready

  for (int jt = 0; jt < NJT; jt++){
    const int j0 = jbase + jt * BJ;
    f32x4 acc[2][8];
#pragma unroll
    for (int mt = 0; mt < 2; mt++)
#pragma unroll
      for (int nt = 0; nt < 8; nt++) acc[mt][nt] = (f32x4)0.f;

    __syncthreads();  // all waves done reading Bs from previous jt
    // stage the FULL K=256 B-slab (64 KB) in one go: 16 async16 per thread
#pragma unroll
    for (int kc = 0; kc < NKC; kc++){
#pragma unroll
      for (int rd = 0; rd < 4; rd++){
        int slot = rd * 256 + tid;           // 16B slots: row = slot>>3, group = slot&7
        int r = slot >> 3, gs = slot & 7;
        int gsrc = (gs ^ (r & 7)) << 3;      // swizzle on the gather side
        ushort_t* ldsB = &Bs[kc][(size_t)(rd * 256 + w * 64) * 8];
        async16(Ebf + (size_t)(j0 + r) * D_K + kc * BK + gsrc, ldsB);
      }
    }
    __syncthreads();  // one drain for the whole slab

#pragma unroll
    for (int kc = 0; kc < NKC; kc++){
#pragma unroll
      for (int s = 0; s < 2; s++){
        const int g = s * 4 + quad;          // k-group within 64-chunk
        const int c = kc * 2 + s;            // A-fragment chunk index
        bf16x8 bfr[8];
#pragma unroll
        for (int nt = 0; nt < 8; nt++){
          int r = nt * 16 + l15;
          bfr[nt] = *reinterpret_cast<const bf16x8*>(&Bs[kc][r * BK + ((g ^ (r & 7)) << 3)]);
        }
#pragma unroll
        for (int nt = 0; nt < 8; nt++){
          acc[0][nt] = __builtin_amdgcn_mfma_f32_16x16x32_bf16(af[0][c], bfr[nt], acc[0][nt], 0, 0, 0);
          acc[1][nt] = __builtin_amdgcn_mfma_f32_16x16x32_bf16(af[1][c], bfr[nt], acc[1][nt], 0, 0, 0);
        }
      }
    }

    // ---- epilogue for this 128-col tile (wave-exclusive rows) ----
    float sqj[8]; int lj[8];
#pragma unroll
    for (int nt = 0; nt < 8; nt++){
      int ccol = jt * BJ + nt * 16 + l15;
      sqj[nt] = s_sqj[ccol]; lj[nt] = s_lj[ccol];
    }
#pragma unroll
    for (int mt = 0; mt < 2; mt++){
#pragma unroll
      for (int rr = 0; rr < 4; rr++){
        int rl = w * 32 + mt * 16 + quad * 4 + rr;   // C/D: row = quad*4+reg, col = l15
        float sqv = s_sqi[rl]; int lrow = s_li[rl]; int jsl = s_ji[rl];
        int sidx = mt * 4 + rr;
        float sv[8];
#pragma unroll
        for (int nt = 0; nt < 8; nt++){
          float a = acc[mt][nt][rr];
          float simv = -10.f * fmaxf(fmaf(-2.f, a, sqv + sqj[nt]), 0.f);
          int colg = j0 + nt * 16 + l15;
          if (colg == jsl) numer[i0 + rl] = simv;    // rare predicated store (numerator)
          sv[nt] = (lj[nt] != lrow) ? simv : NEG_INF; // masks positives + same-label + diag
        }
        float m8 = fmaxf(fmaxf(fmaxf(sv[0],sv[1]),fmaxf(sv[2],sv[3])),
                         fmaxf(fmaxf(sv[4],sv[5]),fmaxf(sv[6],sv[7])));
        float s8 = __expf(sv[0]-m8)+__expf(sv[1]-m8)+__expf(sv[2]-m8)+__expf(sv[3]-m8)
                 + __expf(sv[4]-m8)+__expf(sv[5]-m8)+__expf(sv[6]-m8)+__expf(sv[7]-m8);
        float M = fmaxf(sm[sidx], m8);
        ssum[sidx] = ssum[sidx]*__expf(sm[sidx]-M) + s8*__expf(m8-M);
        sm[sidx] = M;
      }
    }
  }

  // merge the 16 l15-lanes sharing each row; rows are wave-exclusive -> one slot per split
#pragma unroll
  for (int sidx = 0; sidx < 8; sidx++){
    float mv = sm[sidx], sv2 = ssum[sidx];
#pragma unroll
    for (int mask = 1; mask < 16; mask <<= 1){
      float m2 = __shfl_xor(mv, mask);
      float s2 = __shfl_xor(sv2, mask);
      float M = fmaxf(mv, m2);
      sv2 = sv2 * __expf(mv - M) + s2 * __expf(m2 - M);
      mv = M;
    }
    if (l15 == 0){
      int mt = sidx >> 2, rr = sidx & 3;
      int rl = w * 32 + mt * 16 + quad * 4 + rr;
      int o = split * B_N + i0 + rl;
      wsM[o] = mv; wsS[o] = sv2;
    }
  }
}

// ---------------- node 4. finale: 32 blocks, atomic-finish reduction ----------------
__global__ __launch_bounds__(256)
void finale_kernel(const float* __restrict__ wsM, const float* __restrict__ wsS,
                   const float* __restrict__ numer, const int* __restrict__ jsel,
                   float* __restrict__ acc4, float* __restrict__ out)
{
  const int tid = threadIdx.x;
  const int row = blockIdx.x * 256 + tid;   // 32*256 = 8192, one row per thread
  float M = -3.0e38f, S = 0.f;
#pragma unroll
  for (int p = 0; p < NPART; p++){
    float m2 = wsM[p * B_N + row], s2 = wsS[p * B_N + row];
    float Mn = fmaxf(M, m2);
    S = S * __expf(M - Mn) + s2 * __expf(m2 - Mn);
    M = Mn;
  }
  bool v = (jsel[row] >= 0) && (M > -5e29f);
  float s = v ? (M + logf(S) - numer[row]) : 0.f;
  unsigned n = v ? 1u : 0u;
#pragma unroll
  for (int off = 32; off > 0; off >>= 1){ s += __shfl_down(s, off); n += __shfl_down(n, off); }
  __shared__ float ssm[4]; __shared__ unsigned snm[4];
  if ((tid & 63) == 0){ ssm[tid >> 6] = s; snm[tid >> 6] = n; }
  __syncthreads();
  if (tid == 0){
    float bs = ssm[0] + ssm[1] + ssm[2] + ssm[3];
    unsigned bn = snm[0] + snm[1] + snm[2] + snm[3];
    atomicAdd(&acc4[0], bs);
    atomicAdd((unsigned*)&acc4[1], bn);
    __threadfence();
    unsigned old = atomicAdd((unsigned*)&acc4[2], 1u);
    if (old == 31u){  // last block: publish
      float St = atomicAdd(&acc4[0], 0.f);
      unsigned Nt = atomicAdd((unsigned*)&acc4[1], 0u);
      out[0] = (Nt > 0u) ? (St / (float)Nt) : 0.f;
    }
  }
}

extern "C" void kernel_launch(void* const* d_in, const int* in_sizes, int n_in,
                              void* d_out, int out_size, void* d_ws, size_t ws_size,
                              hipStream_t stream)
{
  const float* E      = (const float*)d_in[0];
  const int*   labels = (const int*)d_in[1];
  float*       out    = (float*)d_out;

  ushort_t* Ebf = (ushort_t*)d_ws;                     // 4 MB
  float* wsM    = (float*)(Ebf + (size_t)B_N * D_K);   // 512 KB (16 partials)
  float* wsS    = wsM + NPART * B_N;                   // 512 KB
  float* sqb    = wsS + NPART * B_N;                   // 32 KB
  float* numer  = sqb + B_N;                           // 32 KB
  int* jsel     = (int*)(numer + B_N);                 // 32 KB
  float* acc4   = (float*)(jsel + B_N);                // 16 B accumulators

  prep_kernel<<<B_N / 4, 256, 0, stream>>>(E, Ebf, sqb, acc4);
  classsel_kernel<<<NCLS, 256, 0, stream>>>(labels, jsel);
  fused_kernel<<<(B_N / BI) * NSPLIT, 256, 0, stream>>>(Ebf, labels, sqb, jsel, numer, wsM, wsS);
  finale_kernel<<<B_N / 256, 256, 0, stream>>>(wsM, wsS, numer, jsel, acc4, out);
}